// Round 6
// baseline (167.079 us; speedup 1.0000x reference)
//
#include <hip/hip_runtime.h>

// GradientLoss: sum_c mean( (conv3d_c(x) - conv3d_c(y))^2 ), c in {d,h,w} Sobel dirs.
// conv linear -> conv(x)-conv(y) = conv(x-y). Separable: s=[1,2,1], g=[1,0,-1];
// SAME zero pad; squared output -> flip irrelevant.
//
// R5: barrier-free (R4) + float4 w-vectorization. R4's failure: 12 scalar-dword
// loads/lane/plane (3 load-instrs per output) with a 1-iter load->use window ->
// VMEM-issue/latency bound at 1.5 TB/s. Now each lane owns a float4 w-chunk;
// 56 lanes cover W=224; one output h-row per wave; 6 float4 loads/lane/plane
// (1.5 instr/output, 16B each). w-halo = 2 shuffles/row. h-halo loaded
// redundantly (3x, L1-served: plane row-set = 10.7 KB << 32 KB L1). d = rolling
// 3-plane register history, fully unrolled, 1-plane register prefetch. No LDS,
// no barriers in the d-loop -> loads stay in flight across compute.

#define N_  2
#define D_  160
#define H_  192
#define W_  224
#define PS  (H_ * W_)          // plane stride = 43008

#define TD   8                 // d-planes computed per block

constexpr float SCALE = 1.0f / ((float)N_ * D_ * H_ * W_);

__global__ __launch_bounds__(256, 4)
void grad_loss_kernel(const float* __restrict__ x, const float* __restrict__ y,
                      float* __restrict__ out) {
    __shared__ float wsum[4];

    const int tid  = threadIdx.x;
    const int lane = tid & 63;
    const int wv   = tid >> 6;

    const int h  = blockIdx.y * 4 + wv;        // this wave's output row
    const int nchunks = D_ / TD;               // 20
    const int nb = blockIdx.z / nchunks;
    const int d0 = (blockIdx.z % nchunks) * TD;

    const bool wact = lane < 56;               // 56 lanes x 4 w = 224 = W
    const int  w0   = lane * 4;

    const float* bx = x + (size_t)nb * ((size_t)D_ * PS);
    const float* by = y + (size_t)nb * ((size_t)D_ * PS);

    bool rok[3];
    int  ro[3];
    #pragma unroll
    for (int r = 0; r < 3; ++r) {
        int hr = h - 1 + r;
        rok[r] = ((unsigned)hr < (unsigned)H_) && wact;
        ro[r]  = hr * W_ + w0;                 // +p*PS per plane; fits int
    }

    const float4 z4 = make_float4(0.f, 0.f, 0.f, 0.f);
    float4 vc[3];                               // current plane, rows h-1..h+1
    float4 a0, a1, a2, b0, b1, b2;              // d-history (p-2, p-1)
    float acc = 0.f;

    // ---- prologue: plane d0-1 into vc ----
    {
        const int p = d0 - 1;
        const bool pin = p >= 0;
        #pragma unroll
        for (int r = 0; r < 3; ++r) {
            vc[r] = z4;
            if (pin && rok[r]) {
                const float4 xv = *(const float4*)(bx + p * PS + ro[r]);
                const float4 yv = *(const float4*)(by + p * PS + ro[r]);
                vc[r] = make_float4(xv.x - yv.x, xv.y - yv.y,
                                    xv.z - yv.z, xv.w - yv.w);
            }
        }
    }

    #pragma unroll
    for (int it = 0; it <= TD + 1; ++it) {
        // ---- 1. issue plane (d0+it) float4 loads (land during compute) ----
        float4 xn[3], yn[3];
        const int p = d0 + it;
        const bool pref = (it <= TD) && (p < D_);
        #pragma unroll
        for (int r = 0; r < 3; ++r) {
            xn[r] = z4; yn[r] = z4;
            if (pref && rok[r]) {
                xn[r] = *(const float4*)(bx + p * PS + ro[r]);
                yn[r] = *(const float4*)(by + p * PS + ro[r]);
            }
        }

        // ---- 2. in-plane stencils on vc (plane d0-1+it) ----
        float4 sw[3], gw[3];
        #pragma unroll
        for (int r = 0; r < 3; ++r) {
            float Lm = __shfl_up(vc[r].w, 1, 64);    // w-1 of elem .x
            float Rp = __shfl_down(vc[r].x, 1, 64);  // w+1 of elem .w
            if (lane == 0) Lm = 0.f;                 // w=0 boundary (zero pad)
            // lane 55's Rp comes from lane 56: vc=0 there (wact false) -> pad ok
            const float4 v = vc[r];
            sw[r] = make_float4(Lm + 2.f * v.x + v.y,
                                v.x + 2.f * v.y + v.z,
                                v.y + 2.f * v.z + v.w,
                                v.z + 2.f * v.w + Rp);
            gw[r] = make_float4(Lm - v.y, v.x - v.z, v.y - v.w, v.z - Rp);
        }
        float4 n0 = make_float4(sw[0].x + 2.f * sw[1].x + sw[2].x,
                                sw[0].y + 2.f * sw[1].y + sw[2].y,
                                sw[0].z + 2.f * sw[1].z + sw[2].z,
                                sw[0].w + 2.f * sw[1].w + sw[2].w);   // s_h s_w
        float4 n1 = make_float4(sw[0].x - sw[2].x, sw[0].y - sw[2].y,
                                sw[0].z - sw[2].z, sw[0].w - sw[2].w); // g_h s_w
        float4 n2 = make_float4(gw[0].x + 2.f * gw[1].x + gw[2].x,
                                gw[0].y + 2.f * gw[1].y + gw[2].y,
                                gw[0].z + 2.f * gw[1].z + gw[2].z,
                                gw[0].w + 2.f * gw[1].w + gw[2].w);   // s_h g_w

        // ---- 3. d-combine for center plane (a=p-2, b=p-1, n=p) ----
        if (it >= 2 && wact) {
            float4 gx = make_float4(a0.x - n0.x, a0.y - n0.y,
                                    a0.z - n0.z, a0.w - n0.w);         // g_d s_h s_w
            float4 gy = make_float4(a1.x + 2.f * b1.x + n1.x,
                                    a1.y + 2.f * b1.y + n1.y,
                                    a1.z + 2.f * b1.z + n1.z,
                                    a1.w + 2.f * b1.w + n1.w);         // s_d g_h s_w
            float4 gz = make_float4(a2.x + 2.f * b2.x + n2.x,
                                    a2.y + 2.f * b2.y + n2.y,
                                    a2.z + 2.f * b2.z + n2.z,
                                    a2.w + 2.f * b2.w + n2.w);         // s_d s_h g_w
            acc = fmaf(gx.x, gx.x, acc); acc = fmaf(gx.y, gx.y, acc);
            acc = fmaf(gx.z, gx.z, acc); acc = fmaf(gx.w, gx.w, acc);
            acc = fmaf(gy.x, gy.x, acc); acc = fmaf(gy.y, gy.y, acc);
            acc = fmaf(gy.z, gy.z, acc); acc = fmaf(gy.w, gy.w, acc);
            acc = fmaf(gz.x, gz.x, acc); acc = fmaf(gz.y, gz.y, acc);
            acc = fmaf(gz.z, gz.z, acc); acc = fmaf(gz.w, gz.w, acc);
        }

        // ---- 4. rotate history (renamed away by full unroll) ----
        a0 = b0; a1 = b1; a2 = b2;
        b0 = n0; b1 = n1; b2 = n2;

        // ---- 5. commit prefetched plane (first use -> vmcnt wait here) ----
        #pragma unroll
        for (int r = 0; r < 3; ++r)
            vc[r] = make_float4(xn[r].x - yn[r].x, xn[r].y - yn[r].y,
                                xn[r].z - yn[r].z, xn[r].w - yn[r].w);
    }

    // ---- reduction: wave butterfly, tiny LDS combine, one atomic/block ----
    #pragma unroll
    for (int off = 32; off > 0; off >>= 1)
        acc += __shfl_xor(acc, off, 64);
    if (lane == 0) wsum[wv] = acc;
    __syncthreads();
    if (tid == 0) {
        float s = (wsum[0] + wsum[1]) + (wsum[2] + wsum[3]);
        atomicAdd(out, s * SCALE);
    }
}

extern "C" void kernel_launch(void* const* d_in, const int* in_sizes, int n_in,
                              void* d_out, int out_size, void* d_ws, size_t ws_size,
                              hipStream_t stream) {
    const float* x = (const float*)d_in[0];
    const float* y = (const float*)d_in[1];
    float* out = (float*)d_out;

    hipMemsetAsync(out, 0, sizeof(float), stream);

    dim3 block(256);                    // 4 waves, one h-row each
    dim3 grid(1,                        // one wave spans full W (56x4 = 224)
              H_ / 4,                   // 48
              N_ * (D_ / TD));          // 40  -> 1920 blocks
    grad_loss_kernel<<<grid, block, 0, stream>>>(x, y, out);
}

// Round 7
// 151.725 us; speedup vs baseline: 1.1012x; 1.1012x over previous
//
#include <hip/hip_runtime.h>

// GradientLoss: sum_c mean( (conv3d_c(x) - conv3d_c(y))^2 ), c in {d,h,w} Sobel dirs.
// conv linear -> conv(x)-conv(y) = conv(x-y). Separable: s=[1,2,1], g=[1,0,-1];
// SAME zero pad; squared output -> flip irrelevant.
//
// R6: back to the best structure (R2: LDS staging + rolling register d-history),
// with the two concurrency coefficients fixed:
//   (a) __launch_bounds__(256,8): VGPR 32 / LDS 16.1 KB -> 8 blocks/CU resident
//       (R2 ran ~4.4). Barrier-coupled blocks overlap each other's drains.
//   (b) stage TWO planes per barrier: each thread issues 4 independent float4
//       loads (2 planes x {x,y}) before any LDS write -> 2x loads per vmcnt
//       drain, half the barriers of R2.
// Barrier-free variants (R4/R5) lost to compiler load-serialization (VGPR
// reuse -> ~2 loads in flight); here MLP is enforced by the batched staging.

#define N_  2
#define D_  160
#define H_  192
#define W_  224
#define PS  (H_ * W_)

#define TW  64   // tile width  (threads.x)
#define TH  12   // tile height (3 rows per thread.y)
#define TD  8    // d-planes computed per block (stages TD+2 = 10 = 5 pairs)

constexpr int LROWS = TH + 2;       // 14
constexpr int LCW   = 18;           // float4 chunks per row
constexpr int LCOLS = LCW * 4;      // 72 floats (cols 3..68 used by stencil)
constexpr int NCHUNK = LROWS * LCW; // 252 chunks -> one per thread
constexpr float SCALE = 1.0f / ((float)N_ * D_ * H_ * W_);

__global__ __launch_bounds__(256, 8)
void grad_loss_kernel(const float* __restrict__ x, const float* __restrict__ y,
                      float* __restrict__ out) {
    __shared__ float plane[2][2][LROWS][LCOLS];   // [pair buf][plane in pair]
    __shared__ float wsum[4];

    const int tx  = threadIdx.x;          // 0..63 -> w offset
    const int ty  = threadIdx.y;          // 0..3  -> 3 h-rows each
    const int tid = ty * 64 + tx;

    const int w0 = blockIdx.x * TW;
    const int h0 = blockIdx.y * TH;
    const int nchunks = D_ / TD;          // 20
    const int nb = blockIdx.z / nchunks;
    const int d0 = (blockIdx.z % nchunks) * TD;

    const size_t base = (size_t)nb * ((size_t)D_ * PS);
    const bool active = (w0 + tx) < W_;   // last w-tile half-empty

    // ---- staging assignment: one float4 chunk per thread (both planes) ----
    const bool stager = tid < NCHUNK;
    const int srow = tid / LCW;
    const int sci  = tid - srow * LCW;
    const int gh   = h0 - 1 + srow;
    const int gw0  = w0 - 4 + 4 * sci;                  // 16B aligned
    const bool sok = stager && (unsigned)gh < (unsigned)H_ &&
                     (unsigned)gw0 < (unsigned)W_;
    const float* px = x + base + (size_t)gh * W_ + gw0;
    const float* py = y + base + (size_t)gh * W_ + gw0;
    const int loff = srow * LCOLS + 4 * sci;            // LDS float offset

    // rolling d-history: a = plane k-2, b = plane k-1 (3 output rows each)
    float a0[3], a1[3], a2[3], b0[3], b1[3], b2[3];
    float acc = 0.f;
    const int rbase = 3 * ty;   // window rows rbase..rbase+4

    const float4 z4 = make_float4(0.f, 0.f, 0.f, 0.f);

    #pragma unroll
    for (int it = 0; it < (TD + 2) / 2; ++it) {        // 5 pair-iterations
        const int p0 = d0 - 1 + 2 * it;
        const int p1 = p0 + 1;

        // ---- stage pair (p0,p1): 4 independent float4 loads, then write ----
        float4 xA = z4, yA = z4, xB = z4, yB = z4;
        const bool okA = sok && (p0 >= 0);              // p0 <= d0+7 < D always
        const bool okB = sok && (p1 < D_);              // p1 >= d0 >= 0 always
        if (okA) { xA = *(const float4*)(px + (size_t)p0 * PS);
                   yA = *(const float4*)(py + (size_t)p0 * PS); }
        if (okB) { xB = *(const float4*)(px + (size_t)p1 * PS);
                   yB = *(const float4*)(py + (size_t)p1 * PS); }
        if (stager) {
            *(float4*)(&plane[it & 1][0][0][0] + loff) =
                make_float4(xA.x - yA.x, xA.y - yA.y, xA.z - yA.z, xA.w - yA.w);
            *(float4*)(&plane[it & 1][1][0][0] + loff) =
                make_float4(xB.x - yB.x, xB.y - yB.y, xB.z - yB.z, xB.w - yB.w);
        }
        __syncthreads();
        // one barrier/pair: reads of buf[it&1] (below) are ordered before the
        // it+2 overwrite by the barrier at it+1.

        // ---- process the two freshly staged planes ----
        #pragma unroll
        for (int s = 0; s < 2; ++s) {
            const float (*buf)[LCOLS] = plane[it & 1][s];
            float sw[5], gww[5];
            #pragma unroll
            for (int r = 0; r < 5; ++r) {
                float a = buf[rbase + r][tx + 3];
                float b = buf[rbase + r][tx + 4];
                float c = buf[rbase + r][tx + 5];
                sw[r]  = a + 2.f * b + c;   // s_w
                gww[r] = a - c;             // g_w
            }
            float n0[3], n1[3], n2[3];
            #pragma unroll
            for (int j = 0; j < 3; ++j) {
                n0[j] = sw[j] + 2.f * sw[j + 1] + sw[j + 2];    // s_h s_w
                n1[j] = sw[j] - sw[j + 2];                      // g_h s_w
                n2[j] = gww[j] + 2.f * gww[j + 1] + gww[j + 2]; // s_h g_w
            }

            // combine for center plane (a = k-2, b = k-1, n = k); first two
            // processed planes (it==0) only seed history
            if (it >= 1 && active) {
                #pragma unroll
                for (int j = 0; j < 3; ++j) {
                    float gx = a0[j] - n0[j];                    // g_d s_h s_w
                    float gy = a1[j] + 2.f * b1[j] + n1[j];      // s_d g_h s_w
                    float gz = a2[j] + 2.f * b2[j] + n2[j];      // s_d s_h g_w
                    acc = fmaf(gx, gx, acc);
                    acc = fmaf(gy, gy, acc);
                    acc = fmaf(gz, gz, acc);
                }
            }
            #pragma unroll
            for (int j = 0; j < 3; ++j) {
                a0[j] = b0[j]; a1[j] = b1[j]; a2[j] = b2[j];
                b0[j] = n0[j]; b1[j] = n1[j]; b2[j] = n2[j];
            }
        }
    }

    // ---- block reduction ----
    #pragma unroll
    for (int off = 32; off > 0; off >>= 1)
        acc += __shfl_xor(acc, off, 64);
    if (tx == 0) wsum[ty] = acc;
    __syncthreads();
    if (tid == 0) {
        float s = (wsum[0] + wsum[1]) + (wsum[2] + wsum[3]);
        atomicAdd(out, s * SCALE);
    }
}

extern "C" void kernel_launch(void* const* d_in, const int* in_sizes, int n_in,
                              void* d_out, int out_size, void* d_ws, size_t ws_size,
                              hipStream_t stream) {
    const float* x = (const float*)d_in[0];
    const float* y = (const float*)d_in[1];
    float* out = (float*)d_out;

    hipMemsetAsync(out, 0, sizeof(float), stream);

    dim3 block(TW, 256 / TW);                 // 64 x 4
    dim3 grid((W_ + TW - 1) / TW,             // 4
              H_ / TH,                        // 16
              N_ * (D_ / TD));                // 40  -> 2560 blocks
    grad_loss_kernel<<<grid, block, 0, stream>>>(x, y, out);
}

// Round 8
// 138.082 us; speedup vs baseline: 1.2100x; 1.0988x over previous
//
#include <hip/hip_runtime.h>
#include <stdint.h>

// GradientLoss: sum_c mean( (conv3d_c(x) - conv3d_c(y))^2 ), c in {d,h,w} Sobel dirs.
// conv linear -> conv(x)-conv(y) = conv(x-y). Separable: s=[1,2,1], g=[1,0,-1];
// SAME zero pad; squared output -> flip irrelevant.
//
// R7: break the barrier-drain convoy (R2/R3/R6 all pinned at 58us: ~80K cyc/CU
// of exposed vmcnt(0) drain). Pipeline:
//   - global->LDS DMA (__builtin_amdgcn_global_load_lds, 16B/lane): no VGPR
//     round-trip, deep in-flight queue (MLP lives in the DMA queue, not waves)
//   - triple-buffered LDS, prefetch distance 2: at iter i, stage plane i+2,
//     compute plane i
//   - inline-asm "s_waitcnt vmcnt(5); s_barrier" instead of __syncthreads:
//     waits exactly for the plane needed NOW, leaves the fresh prefetch in
//     flight. Every wave issues exactly 5 DMAs/iter (clamped addresses at all
//     boundaries; zeroed later via masks) so the per-wave vmcnt budget is
//     uniform and correct.
//   - compute = R5 shuffle stencil from LDS float4 reads; no ds_writes at all.
// LDS 60KB -> 2 blocks/CU (occupancy is NOT the concurrency mechanism here).

#define N_  2
#define D_  160
#define H_  192
#define W_  224
#define PS  (H_ * W_)

#define TD  8                  // d-planes computed per block
#define TH  8                  // h output rows per block (2 per wave)
constexpr int SROWS = TH + 2;  // 10 staged rows per plane
constexpr int RPAD  = 256;     // floats per LDS row slot (1 KB; [224,256) = pad)
constexpr float SCALE = 1.0f / ((float)N_ * D_ * H_ * W_);

#define DMA16(gp, lp) __builtin_amdgcn_global_load_lds(                        \
    (const __attribute__((address_space(1))) void*)(gp),                       \
    (__attribute__((address_space(3))) void*)(lp), 16, 0, 0)

__global__ __launch_bounds__(256, 2)
void grad_loss_kernel(const float* __restrict__ x, const float* __restrict__ y,
                      float* __restrict__ out) {
    __shared__ float sbuf[3][SROWS][2][RPAD];   // 3 bufs x 10 rows x {x,y} x 1KB
    __shared__ float wsum[4];

    const int tid  = threadIdx.x;
    const int lane = tid & 63;
    const int wv   = tid >> 6;

    const int h0 = blockIdx.y * TH;
    const int nchunks = D_ / TD;               // 20
    const int nb = blockIdx.z / nchunks;
    const int d0 = (blockIdx.z % nchunks) * TD;

    const float* vbx = x + (size_t)nb * ((size_t)D_ * PS);
    const float* vby = y + (size_t)nb * ((size_t)D_ * PS);

    // per-lane source float offset within a row; lanes 56..63 duplicate lane 55
    // (their LDS bytes land in the row pad [896,1024) and are never read)
    const int lo = (lane < 56 ? lane : 55) * 4;

    // ---- 5 wave-uniform staging items per wave: item = (row l, array a) ----
    int sl[5], sa[5], srw[5];
    const float* sb[5];
    #pragma unroll
    for (int k = 0; k < 5; ++k) {
        int item = 5 * wv + k;                 // 20 items over 4 waves
        sl[k] = item >> 1;
        sa[k] = item & 1;
        int gh  = h0 - 1 + sl[k];
        int ghc = min(max(gh, 0), H_ - 1);     // clamped; zeroed via rmask later
        srw[k] = ghc * W_;
        sb[k]  = sa[k] ? vby : vbx;
    }

    auto stage = [&](int p, int bsel) {
        int pc = min(max(p, 0), D_ - 1);       // clamped; zeroed via pm later
        size_t poff = (size_t)pc * PS;
        #pragma unroll
        for (int k = 0; k < 5; ++k)
            DMA16(sb[k] + poff + srw[k] + lo, &sbuf[bsel][sl[k]][sa[k]][0]);
    };

    // ---- compute-side masks ----
    const bool wact = lane < 56;               // 56 lanes x 4 = 224 = W
    float rmask[4];
    #pragma unroll
    for (int r = 0; r < 4; ++r) {              // wave reads staged rows 2wv..2wv+3
        int gh = h0 - 1 + 2 * wv + r;
        rmask[r] = (((unsigned)gh < (unsigned)H_) && wact) ? 1.f : 0.f;
    }
    const int lrd = lane * 4;                  // LDS read offset (floats)

    float4 A0[2], A1[2], A2[2], B0[2], B1[2], B2[2];   // d-history (p-2, p-1)
    const float4 z4 = make_float4(0.f, 0.f, 0.f, 0.f);
    #pragma unroll
    for (int j = 0; j < 2; ++j) { A0[j]=A1[j]=A2[j]=B0[j]=B1[j]=B2[j]=z4; }
    float acc = 0.f;

    // ---- prologue: plane d0-1 -> buf0, plane d0 -> buf1 (order matters) ----
    stage(d0 - 1, 0);
    asm volatile("" ::: "memory");             // keep the two DMA groups ordered
    stage(d0, 1);

    #pragma unroll
    for (int it = 0; it < TD + 2; ++it) {
        // wait for the plane computed this iter (issued 2 groups ago), leave
        // the newest 5 DMAs in flight; then rendezvous.
        if (it == TD + 1)
            asm volatile("s_waitcnt vmcnt(0)\n\ts_barrier" ::: "memory");
        else
            asm volatile("s_waitcnt vmcnt(5)\n\ts_barrier" ::: "memory");

        // stage plane d0+1+it into buf[(it+2)%3] (safe: all waves passed the
        // barrier, so nobody still reads that buffer)
        if (it <= TD - 1) stage(d0 + 1 + it, (it + 2) % 3);

        const int q = d0 - 1 + it;             // plane processed this iter
        const float pm = (q >= 0 && q < D_) ? 1.f : 0.f;
        const int bsel = it % 3;

        // ---- in-plane stencils from LDS (float4 + 2 shuffles per row) ----
        float4 sw[4], gw[4];
        #pragma unroll
        for (int r = 0; r < 4; ++r) {
            const int l = 2 * wv + r;
            const float4 xr = *(const float4*)&sbuf[bsel][l][0][lrd];
            const float4 yr = *(const float4*)&sbuf[bsel][l][1][lrd];
            const float m = rmask[r] * pm;
            float4 v = make_float4((xr.x - yr.x) * m, (xr.y - yr.y) * m,
                                   (xr.z - yr.z) * m, (xr.w - yr.w) * m);
            float Lm = __shfl_up(v.w, 1, 64);
            float Rp = __shfl_down(v.x, 1, 64);
            if (lane == 0) Lm = 0.f;           // w = -1 zero pad
            // lane 55's Rp comes from lane 56: v there is 0 (wact mask) ✓
            sw[r] = make_float4(Lm + 2.f * v.x + v.y,
                                v.x + 2.f * v.y + v.z,
                                v.y + 2.f * v.z + v.w,
                                v.z + 2.f * v.w + Rp);
            gw[r] = make_float4(Lm - v.y, v.x - v.z, v.y - v.w, v.z - Rp);
        }
        float4 n0[2], n1[2], n2[2];
        #pragma unroll
        for (int j = 0; j < 2; ++j) {
            n0[j] = make_float4(sw[j].x + 2.f * sw[j+1].x + sw[j+2].x,
                                sw[j].y + 2.f * sw[j+1].y + sw[j+2].y,
                                sw[j].z + 2.f * sw[j+1].z + sw[j+2].z,
                                sw[j].w + 2.f * sw[j+1].w + sw[j+2].w);  // s_h s_w
            n1[j] = make_float4(sw[j].x - sw[j+2].x, sw[j].y - sw[j+2].y,
                                sw[j].z - sw[j+2].z, sw[j].w - sw[j+2].w); // g_h s_w
            n2[j] = make_float4(gw[j].x + 2.f * gw[j+1].x + gw[j+2].x,
                                gw[j].y + 2.f * gw[j+1].y + gw[j+2].y,
                                gw[j].z + 2.f * gw[j+1].z + gw[j+2].z,
                                gw[j].w + 2.f * gw[j+1].w + gw[j+2].w);  // s_h g_w
        }

        // ---- d-combine for center plane q-1 (A = q-2, B = q-1, n = q) ----
        if (it >= 2 && wact) {
            #pragma unroll
            for (int j = 0; j < 2; ++j) {
                float4 gx = make_float4(A0[j].x - n0[j].x, A0[j].y - n0[j].y,
                                        A0[j].z - n0[j].z, A0[j].w - n0[j].w);
                float4 gy = make_float4(A1[j].x + 2.f * B1[j].x + n1[j].x,
                                        A1[j].y + 2.f * B1[j].y + n1[j].y,
                                        A1[j].z + 2.f * B1[j].z + n1[j].z,
                                        A1[j].w + 2.f * B1[j].w + n1[j].w);
                float4 gz = make_float4(A2[j].x + 2.f * B2[j].x + n2[j].x,
                                        A2[j].y + 2.f * B2[j].y + n2[j].y,
                                        A2[j].z + 2.f * B2[j].z + n2[j].z,
                                        A2[j].w + 2.f * B2[j].w + n2[j].w);
                acc = fmaf(gx.x, gx.x, acc); acc = fmaf(gx.y, gx.y, acc);
                acc = fmaf(gx.z, gx.z, acc); acc = fmaf(gx.w, gx.w, acc);
                acc = fmaf(gy.x, gy.x, acc); acc = fmaf(gy.y, gy.y, acc);
                acc = fmaf(gy.z, gy.z, acc); acc = fmaf(gy.w, gy.w, acc);
                acc = fmaf(gz.x, gz.x, acc); acc = fmaf(gz.y, gz.y, acc);
                acc = fmaf(gz.z, gz.z, acc); acc = fmaf(gz.w, gz.w, acc);
            }
        }

        // ---- rotate history (renamed by full unroll) ----
        #pragma unroll
        for (int j = 0; j < 2; ++j) {
            A0[j] = B0[j]; A1[j] = B1[j]; A2[j] = B2[j];
            B0[j] = n0[j]; B1[j] = n1[j]; B2[j] = n2[j];
        }
    }

    // ---- reduction: wave butterfly, LDS combine, one atomic per block ----
    #pragma unroll
    for (int off = 32; off > 0; off >>= 1)
        acc += __shfl_xor(acc, off, 64);
    if (lane == 0) wsum[wv] = acc;
    __syncthreads();
    if (tid == 0) {
        float s = (wsum[0] + wsum[1]) + (wsum[2] + wsum[3]);
        atomicAdd(out, s * SCALE);
    }
}

extern "C" void kernel_launch(void* const* d_in, const int* in_sizes, int n_in,
                              void* d_out, int out_size, void* d_ws, size_t ws_size,
                              hipStream_t stream) {
    const float* x = (const float*)d_in[0];
    const float* y = (const float*)d_in[1];
    float* out = (float*)d_out;

    hipMemsetAsync(out, 0, sizeof(float), stream);

    dim3 block(256);                    // 4 waves; one wave = full W x 2 h-rows
    dim3 grid(1,
              H_ / TH,                  // 24
              N_ * (D_ / TD));          // 40  -> 960 blocks
    grad_loss_kernel<<<grid, block, 0, stream>>>(x, y, out);
}